// Round 3
// baseline (539.581 us; speedup 1.0000x reference)
//
#include <hip/hip_runtime.h>

#define T_TOT 100
#define BATCH 512
#define FIN   784
#define HID   1024
#define NOUT  10
#define KP    800      // K padded to multiple of 32
#define BK    32
#define KSTEPS 25      // KP / BK

#define BM 128
#define BN 128
#define BUFSZ 32768    // Ahi 8K | Alo 8K | Bhi 8K | Blo 8K
#define A_HI 0
#define A_LO 8192
#define B_HI 16384
#define B_LO 24576

typedef _Float16 f16x8 __attribute__((ext_vector_type(8)));
typedef float    f32x4 __attribute__((ext_vector_type(4)));

#define AS1C(p) ((const __attribute__((address_space(1))) void*)(p))
#define AS3(p)  ((__attribute__((address_space(3))) void*)(p))

// ---------------------------------------------------------------------------
// fp32 -> fp16 hi/lo split, row length 784 padded to 800.
//   hi = fp16(x);  lo = fp16((x - hi) * 4096)
// ---------------------------------------------------------------------------
__global__ __launch_bounds__(256)
void cvt_split(const float* __restrict__ src, _Float16* __restrict__ hi,
               _Float16* __restrict__ lo, int nrows)
{
    int idx = blockIdx.x * 256 + threadIdx.x;
    if (idx >= nrows * 100) return;
    int row = idx / 100;
    int k0  = (idx - row * 100) * 8;
    f16x8 h, l;
    if (k0 < FIN) {
        float4 a = *(const float4*)(src + (size_t)row * FIN + k0);
        float4 b = *(const float4*)(src + (size_t)row * FIN + k0 + 4);
        float xs[8] = {a.x, a.y, a.z, a.w, b.x, b.y, b.z, b.w};
        #pragma unroll
        for (int j = 0; j < 8; ++j) {
            _Float16 hh = (_Float16)xs[j];
            h[j] = hh;
            l[j] = (_Float16)((xs[j] - (float)hh) * 4096.0f);
        }
    } else {
        #pragma unroll
        for (int j = 0; j < 8; ++j) { h[j] = (_Float16)0.f; l[j] = (_Float16)0.f; }
    }
    *(f16x8*)(hi + (size_t)row * KP + k0) = h;
    *(f16x8*)(lo + (size_t)row * KP + k0) = l;
}

// ---------------------------------------------------------------------------
// Z = Xsplit · Wsplit^T + bias, fp16 MFMA 3-term split.
// 128x128 tile, BK=32, 512 thr = 8 waves (4m x 2n), wave tile 32x64.
// Triple-buffered LDS (3 x 32KB), counted vmcnt(4) + raw s_barrier:
// stage(kt+2) issued each iter, loads stay in flight across barriers.
// ---------------------------------------------------------------------------
__global__ __launch_bounds__(512, 2)
void gemm_mfma(const _Float16* __restrict__ Xhi, const _Float16* __restrict__ Xlo,
               const _Float16* __restrict__ Whi, const _Float16* __restrict__ Wlo,
               const float* __restrict__ bias, float* __restrict__ Z, int mb)
{
    __shared__ char smem[3 * BUFSZ];   // 96 KB
    const int tid  = threadIdx.x;
    const int lane = tid & 63;
    const int wid  = tid >> 6;
    const int wm   = wid >> 1;    // 0..3
    const int wn   = wid & 1;     // 0..1
    const int fr   = lane & 15;
    const int fg   = lane >> 4;

    const int j = blockIdx.x;
    int bm, bn;
    if ((mb & 7) == 0) {          // XCD-chunked: xcd = j&7 owns mb/8 slabs
        const int x = j & 7, r = j >> 3;
        bm = x * (mb >> 3) + (r >> 3);
        bn = r & 7;
    } else {
        bm = j >> 3;
        bn = j & 7;
    }
    const size_t row0 = (size_t)bm * BM;
    const int    col0 = bn * BN;

    // stage one K-tile (32KB) into buffer b: 4 x global_load_lds(16B) / thread
    const int srow = tid >> 2;                       // 0..127
    const int spos = tid & 3;
    const int sgg  = spos ^ ((srow >> 1) & 3);       // inverse chunk swizzle
    const size_t gax = (row0 + srow) * (size_t)KP + sgg * 8;
    const size_t gbx = (size_t)(col0 + srow) * KP + sgg * 8;
    const int ldsw = wid * 1024;                     // wave-uniform dest base

    auto stage = [&](int buf, int kt) {
        const int kof = kt * BK;
        const char* dummy;
        char* base = smem + buf * BUFSZ + ldsw;
        __builtin_amdgcn_global_load_lds(AS1C(Xhi + gax + kof), AS3(base + A_HI), 16, 0, 0);
        __builtin_amdgcn_global_load_lds(AS1C(Xlo + gax + kof), AS3(base + A_LO), 16, 0, 0);
        __builtin_amdgcn_global_load_lds(AS1C(Whi + gbx + kof), AS3(base + B_HI), 16, 0, 0);
        __builtin_amdgcn_global_load_lds(AS1C(Wlo + gbx + kof), AS3(base + B_LO), 16, 0, 0);
        (void)dummy;
    };

    f32x4 accm[2][4], accc[2][4];
    #pragma unroll
    for (int a = 0; a < 2; ++a)
        #pragma unroll
        for (int b = 0; b < 4; ++b) {
            accm[a][b] = (f32x4){0.f, 0.f, 0.f, 0.f};
            accc[a][b] = (f32x4){0.f, 0.f, 0.f, 0.f};
        }

    auto compute = [&](int buf) {
        const char* base = smem + buf * BUFSZ;
        f16x8 ah[2], al[2], bh[4], bl[4];
        #pragma unroll
        for (int mf = 0; mf < 2; ++mf) {
            const int row = wm * 32 + mf * 16 + fr;
            const int off = row * 64 + ((fg ^ ((row >> 1) & 3)) << 4);
            ah[mf] = *(const f16x8*)(base + A_HI + off);
            al[mf] = *(const f16x8*)(base + A_LO + off);
        }
        #pragma unroll
        for (int nf = 0; nf < 4; ++nf) {
            const int row = wn * 64 + nf * 16 + fr;
            const int off = row * 64 + ((fg ^ ((row >> 1) & 3)) << 4);
            bh[nf] = *(const f16x8*)(base + B_HI + off);
            bl[nf] = *(const f16x8*)(base + B_LO + off);
        }
        __builtin_amdgcn_s_setprio(1);
        #pragma unroll
        for (int mf = 0; mf < 2; ++mf)
            #pragma unroll
            for (int nf = 0; nf < 4; ++nf) {
                accm[mf][nf] = __builtin_amdgcn_mfma_f32_16x16x32_f16(ah[mf], bh[nf], accm[mf][nf], 0, 0, 0);
                accc[mf][nf] = __builtin_amdgcn_mfma_f32_16x16x32_f16(ah[mf], bl[nf], accc[mf][nf], 0, 0, 0);
                accc[mf][nf] = __builtin_amdgcn_mfma_f32_16x16x32_f16(al[mf], bh[nf], accc[mf][nf], 0, 0, 0);
            }
        __builtin_amdgcn_s_setprio(0);
    };

    stage(0, 0);
    stage(1, 1);
    for (int kt = 0; kt < KSTEPS; ++kt) {
        if (kt < KSTEPS - 1) asm volatile("s_waitcnt vmcnt(4)" ::: "memory");
        else                 asm volatile("s_waitcnt vmcnt(0)" ::: "memory");
        __builtin_amdgcn_s_barrier();
        if (kt + 2 < KSTEPS) stage((kt + 2) % 3, kt + 2);
        compute(kt % 3);
    }

    #pragma unroll
    for (int nf = 0; nf < 4; ++nf) {
        const int colg = col0 + wn * 64 + nf * 16 + fr;
        const float bv = bias[colg];
        #pragma unroll
        for (int mf = 0; mf < 2; ++mf) {
            const size_t rowg = row0 + wm * 32 + mf * 16 + fg * 4;
            #pragma unroll
            for (int i = 0; i < 4; ++i)
                Z[(rowg + i) * HID + colg] =
                    accm[mf][nf][i] + accc[mf][nf][i] * 2.44140625e-4f + bv;
        }
    }
}

// ---------------------------------------------------------------------------
// DPP 4-level add-reduce: returns per-16-lane-group sum (pure VALU, no LDS)
// ---------------------------------------------------------------------------
__device__ __forceinline__ float dpp_sum16(float v)
{
    int x;
    x = __builtin_amdgcn_update_dpp(0, __builtin_bit_cast(int, v), 0xB1, 0xF, 0xF, true);  // quad xor1
    v += __builtin_bit_cast(float, x);
    x = __builtin_amdgcn_update_dpp(0, __builtin_bit_cast(int, v), 0x4E, 0xF, 0xF, true);  // quad xor2
    v += __builtin_bit_cast(float, x);
    x = __builtin_amdgcn_update_dpp(0, __builtin_bit_cast(int, v), 0x141, 0xF, 0xF, true); // row_half_mirror
    v += __builtin_bit_cast(float, x);
    x = __builtin_amdgcn_update_dpp(0, __builtin_bit_cast(int, v), 0x140, 0xF, 0xF, true); // row_mirror
    v += __builtin_bit_cast(float, x);
    return v;
}

// ---------------------------------------------------------------------------
// Fused LIF + LI scan. DPP reduce (VALU) replaces the 60-bpermute butterfly.
// ---------------------------------------------------------------------------
__global__ __launch_bounds__(256, 2)
void lif_scan(const float* __restrict__ Z, const float* __restrict__ Wout,
              float* __restrict__ out,
              float* __restrict__ st_v, float* __restrict__ st_i,
              float* __restrict__ st_vli, float* __restrict__ st_ili,
              int t0, int tn, int first, int last)
{
#pragma clang fp contract(off)   // mirror numpy's unfused mul/add rounding
    __shared__ float Wlds[NOUT][HID];
    __shared__ float red[2][16][NOUT];

    const int tid  = threadIdx.x;
    const int b    = blockIdx.x;
    const int h4   = tid * 4;
    const int lane = tid & 63;
    const int wv   = tid >> 6;

    #pragma unroll
    for (int o = 0; o < NOUT; ++o)
        *(float4*)&Wlds[o][h4] = *(const float4*)&Wout[o * HID + h4];

    float v[4], cu[4];
    if (first) {
        #pragma unroll
        for (int j = 0; j < 4; ++j) { v[j] = 0.f; cu[j] = 0.f; }
    } else {
        float4 tv = *(const float4*)&st_v[(size_t)b*HID + h4];
        float4 ti = *(const float4*)&st_i[(size_t)b*HID + h4];
        v[0]=tv.x; v[1]=tv.y; v[2]=tv.z; v[3]=tv.w;
        cu[0]=ti.x; cu[1]=ti.y; cu[2]=ti.z; cu[3]=ti.w;
    }
    float vli = 0.f, ili = 0.f;
    if (!first && tid < NOUT) {
        vli = st_vli[b*NOUT + tid];
        ili = st_ili[b*NOUT + tid];
    }

    __syncthreads();

    const float* Zb = Z + (size_t)b * HID + h4;
    float4 zn  = *(const float4*)Zb;                                     // t
    float4 znn = (tn > 1) ? *(const float4*)(Zb + (size_t)BATCH * HID)   // t+1
                          : zn;

    for (int t = 0; t < tn; ++t) {
        float4 zc = zn;
        zn = znn;
        if (t + 2 < tn) znn = *(const float4*)(Zb + (size_t)(t+2) * BATCH * HID);

        const float za[4] = {zc.x, zc.y, zc.z, zc.w};
        float zf[4];
        bool anyz = false;
        #pragma unroll
        for (int j = 0; j < 4; ++j) {
            float tmp  = (0.0f - v[j]) + cu[j];
            float vdec = v[j] + 0.1f * tmp;
            bool  z    = vdec > 1.0f;
            zf[j] = z ? 1.0f : 0.0f;
            anyz  = anyz || z;
            v[j]  = z ? 0.0f : vdec;
            cu[j] = cu[j] * 0.8f + za[j];
        }

        float p[NOUT];
        #pragma unroll
        for (int o = 0; o < NOUT; ++o) p[o] = 0.f;

        if (__any(anyz)) {
            if (anyz) {
                #pragma unroll
                for (int o = 0; o < NOUT; ++o) {
                    float4 w = *(const float4*)&Wlds[o][h4];
                    p[o] = zf[0]*w.x + zf[1]*w.y + zf[2]*w.z + zf[3]*w.w;
                }
            }
            #pragma unroll
            for (int o = 0; o < NOUT; ++o) p[o] = dpp_sum16(p[o]);  // VALU reduce
        }

        const int par = t & 1;
        if ((lane & 15) == 0) {
            const int g = wv * 4 + (lane >> 4);
            #pragma unroll
            for (int o = 0; o < NOUT; ++o) red[par][g][o] = p[o];
        }
        __syncthreads();
        if (tid < NOUT) {
            float s = 0.f;
            #pragma unroll
            for (int g = 0; g < 16; ++g) s += red[par][g][tid];
            float tmp  = (0.0f - vli) + ili;
            float vnew = vli + 0.1f * tmp;
            ili = ili * 0.8f + s;
            vli = vnew;
            out[((size_t)(t0 + t) * BATCH + b) * NOUT + tid] = vnew;
        }
    }

    if (!last) {
        *(float4*)&st_v[(size_t)b*HID + h4] = make_float4(v[0], v[1], v[2], v[3]);
        *(float4*)&st_i[(size_t)b*HID + h4] = make_float4(cu[0], cu[1], cu[2], cu[3]);
        if (tid < NOUT) { st_vli[b*NOUT + tid] = vli; st_ili[b*NOUT + tid] = ili; }
    }
}

// ---------------------------------------------------------------------------
extern "C" void kernel_launch(void* const* d_in, const int* in_sizes, int n_in,
                              void* d_out, int out_size, void* d_ws, size_t ws_size,
                              hipStream_t stream)
{
    const float* x    = (const float*)d_in[0];   // [100, 512, 784]
    const float* W0   = (const float*)d_in[1];   // [1024, 784]
    const float* b0   = (const float*)d_in[2];   // [1024]
    const float* Wout = (const float*)d_in[3];   // [10, 1024]
    float* out = (float*)d_out;                  // [100, 512, 10]

    char* ws = (char*)d_ws;
    float* st_v   = (float*)ws;                          // 512*1024
    float* st_i   = st_v   + (size_t)BATCH * HID;        // 512*1024
    float* st_vli = st_i   + (size_t)BATCH * HID;        // 512*10
    float* st_ili = st_vli + BATCH * NOUT;               // 512*10
    _Float16* Whi = (_Float16*)(st_ili + BATCH * NOUT);  // 1024*800
    _Float16* Wlo = Whi + (size_t)HID * KP;              // 1024*800
    char* dyn = (char*)(Wlo + (size_t)HID * KP);

    const size_t fixed = (size_t)(dyn - ws);
    const size_t per_t = (size_t)BATCH * HID * 4          // Zbuf
                       + (size_t)BATCH * KP * 2 * 2;      // Xhi + Xlo
    size_t avail = (ws_size > fixed) ? ws_size - fixed : 0;
    int tch = (int)(avail / per_t);
    if (tch > T_TOT) tch = T_TOT;
    if (tch >= 4) tch &= ~3;          // keep mb % 8 == 0 for the XCD swizzle
    if (tch < 1) tch = 1;

    float*    Zbuf = (float*)dyn;
    _Float16* Xhi  = (_Float16*)(dyn + (size_t)tch * BATCH * HID * 4);
    _Float16* Xlo  = Xhi + (size_t)tch * BATCH * KP;

    // W conversion once
    hipLaunchKernelGGL(cvt_split, dim3((HID * 100 + 255) / 256), dim3(256), 0, stream,
                       W0, Whi, Wlo, HID);

    for (int t0 = 0; t0 < T_TOT; t0 += tch) {
        const int tn    = (T_TOT - t0 < tch) ? (T_TOT - t0) : tch;
        const int nrows = tn * BATCH;
        const int mb    = nrows / BM;

        hipLaunchKernelGGL(cvt_split, dim3((nrows * 100 + 255) / 256), dim3(256), 0, stream,
                           x + (size_t)t0 * BATCH * FIN, Xhi, Xlo, nrows);
        hipLaunchKernelGGL(gemm_mfma, dim3(mb * 8), dim3(512), 0, stream,
                           Xhi, Xlo, Whi, Wlo, b0, Zbuf, mb);
        hipLaunchKernelGGL(lif_scan, dim3(BATCH), dim3(256), 0, stream,
                           Zbuf, Wout, out, st_v, st_i, st_vli, st_ili,
                           t0, tn, (t0 == 0) ? 1 : 0, (t0 + tn >= T_TOT) ? 1 : 0);
    }
}

// Round 4
// 525.687 us; speedup vs baseline: 1.0264x; 1.0264x over previous
//
#include <hip/hip_runtime.h>

#define T_TOT 100
#define BATCH 512
#define FIN   784
#define HID   1024
#define NOUT  10
#define KP    800      // K padded to multiple of 32
#define BK    32
#define KSTEPS 25      // KP / BK
#define NGRP  16       // partial-sum groups per batch row (4 waves x 4)

typedef _Float16 f16x8 __attribute__((ext_vector_type(8)));
typedef float    f32x4 __attribute__((ext_vector_type(4)));

#define AS1C(p) ((const __attribute__((address_space(1))) void*)(p))
#define AS3(p)  ((__attribute__((address_space(3))) void*)(p))

// ---------------------------------------------------------------------------
// fp32 -> fp16 hi/lo split, row length 784 padded to 800.
//   hi = fp16(x);  lo = fp16((x - hi) * 4096)
// ---------------------------------------------------------------------------
__global__ __launch_bounds__(256)
void cvt_split(const float* __restrict__ src, _Float16* __restrict__ hi,
               _Float16* __restrict__ lo, int nrows)
{
    int idx = blockIdx.x * 256 + threadIdx.x;
    if (idx >= nrows * 100) return;
    int row = idx / 100;
    int k0  = (idx - row * 100) * 8;
    f16x8 h, l;
    if (k0 < FIN) {
        float4 a = *(const float4*)(src + (size_t)row * FIN + k0);
        float4 b = *(const float4*)(src + (size_t)row * FIN + k0 + 4);
        float xs[8] = {a.x, a.y, a.z, a.w, b.x, b.y, b.z, b.w};
        #pragma unroll
        for (int j = 0; j < 8; ++j) {
            _Float16 hh = (_Float16)xs[j];
            h[j] = hh;
            l[j] = (_Float16)((xs[j] - (float)hh) * 4096.0f);
        }
    } else {
        #pragma unroll
        for (int j = 0; j < 8; ++j) { h[j] = (_Float16)0.f; l[j] = (_Float16)0.f; }
    }
    *(f16x8*)(hi + (size_t)row * KP + k0) = h;
    *(f16x8*)(lo + (size_t)row * KP + k0) = l;
}

// ---------------------------------------------------------------------------
// Z = Xsplit · Wsplit^T + bias, fp16 MFMA 3-term split.  (round-2 structure:
// 128x128 tile, BK=32, 256 thr = 4 waves 2x2, wave tile 64x64, double-buffered
// 64KB LDS, global_load_lds w16, chunk XOR swizzle both sides, drain at bar.)
// ---------------------------------------------------------------------------
__global__ __launch_bounds__(256, 2)
void gemm_mfma(const _Float16* __restrict__ Xhi, const _Float16* __restrict__ Xlo,
               const _Float16* __restrict__ Whi, const _Float16* __restrict__ Wlo,
               const float* __restrict__ bias, float* __restrict__ Z, int mb)
{
    __shared__ char smem[65536];
    const int tid  = threadIdx.x;
    const int lane = tid & 63;
    const int wid  = tid >> 6;
    const int wm   = wid >> 1;
    const int wn   = wid & 1;
    const int fr   = lane & 15;
    const int fg   = lane >> 4;

    const int j = blockIdx.x;
    int bm, bn;
    if ((mb & 7) == 0) {          // XCD-friendly: all 8 bn of a bm share blockIdx%8
        bm = (j & 7) | ((j >> 6) << 3);
        bn = (j >> 3) & 7;
    } else {
        bm = j >> 3;
        bn = j & 7;
    }
    const size_t row0 = (size_t)bm * 128;
    const int    col0 = bn * 128;

    f32x4 accm[4][4], accc[4][4];
    #pragma unroll
    for (int a = 0; a < 4; ++a)
        #pragma unroll
        for (int b = 0; b < 4; ++b) {
            accm[a][b] = (f32x4){0.f, 0.f, 0.f, 0.f};
            accc[a][b] = (f32x4){0.f, 0.f, 0.f, 0.f};
        }

    auto stage = [&](int buf, int kt) {
        const int kof = kt * BK;
        #pragma unroll
        for (int q = 0; q < 2; ++q) {
            const int lin = q * 256 + tid;       // 0..511 16B slots
            const int row = lin >> 2;            // 0..127
            const int pos = lin & 3;             // chunk slot in LDS
            const int gg  = pos ^ ((row >> 1) & 3);  // inverse chunk swizzle
            const int ldsw = buf * 32768 + q * 4096 + wid * 1024;
            const size_t ga = (row0 + row) * (size_t)KP + kof + gg * 8;
            const size_t gb = (size_t)(col0 + row) * KP + kof + gg * 8;
            __builtin_amdgcn_global_load_lds(AS1C(Xhi + ga), AS3(smem + ldsw),         16, 0, 0);
            __builtin_amdgcn_global_load_lds(AS1C(Xlo + ga), AS3(smem + ldsw +  8192), 16, 0, 0);
            __builtin_amdgcn_global_load_lds(AS1C(Whi + gb), AS3(smem + ldsw + 16384), 16, 0, 0);
            __builtin_amdgcn_global_load_lds(AS1C(Wlo + gb), AS3(smem + ldsw + 24576), 16, 0, 0);
        }
    };

    auto compute = [&](int buf) {
        const char* base = smem + buf * 32768;
        f16x8 ah[4], al[4], bh[4], bl[4];
        #pragma unroll
        for (int mf = 0; mf < 4; ++mf) {
            const int row = wm * 64 + mf * 16 + fr;
            const int off = row * 64 + ((fg ^ ((row >> 1) & 3)) << 4);
            ah[mf] = *(const f16x8*)(base + off);
            al[mf] = *(const f16x8*)(base + 8192 + off);
        }
        #pragma unroll
        for (int nf = 0; nf < 4; ++nf) {
            const int row = wn * 64 + nf * 16 + fr;
            const int off = row * 64 + ((fg ^ ((row >> 1) & 3)) << 4);
            bh[nf] = *(const f16x8*)(base + 16384 + off);
            bl[nf] = *(const f16x8*)(base + 24576 + off);
        }
        #pragma unroll
        for (int mf = 0; mf < 4; ++mf)
            #pragma unroll
            for (int nf = 0; nf < 4; ++nf) {
                accm[mf][nf] = __builtin_amdgcn_mfma_f32_16x16x32_f16(ah[mf], bh[nf], accm[mf][nf], 0, 0, 0);
                accc[mf][nf] = __builtin_amdgcn_mfma_f32_16x16x32_f16(ah[mf], bl[nf], accc[mf][nf], 0, 0, 0);
                accc[mf][nf] = __builtin_amdgcn_mfma_f32_16x16x32_f16(al[mf], bh[nf], accc[mf][nf], 0, 0, 0);
            }
    };

    stage(0, 0);
    int buf = 0;
    for (int kt = 0; kt < KSTEPS; ++kt) {
        __syncthreads();                       // drains vmcnt -> buf ready
        if (kt + 1 < KSTEPS) stage(buf ^ 1, kt + 1);
        compute(buf);
        buf ^= 1;
    }

    #pragma unroll
    for (int nf = 0; nf < 4; ++nf) {
        const int colg = col0 + wn * 64 + nf * 16 + fr;
        const float bv = bias[colg];
        #pragma unroll
        for (int mf = 0; mf < 4; ++mf) {
            const size_t rowg = row0 + wm * 64 + mf * 16 + fg * 4;
            #pragma unroll
            for (int i = 0; i < 4; ++i)
                Z[(rowg + i) * HID + colg] =
                    accm[mf][nf][i] + accc[mf][nf][i] * 2.44140625e-4f + bv;
        }
    }
}

// ---------------------------------------------------------------------------
// DPP 4-level add-reduce: per-16-lane-group sum, result in ALL lanes (VALU)
// ---------------------------------------------------------------------------
__device__ __forceinline__ float dpp_sum16(float v)
{
    int x;
    x = __builtin_amdgcn_update_dpp(0, __builtin_bit_cast(int, v), 0xB1, 0xF, 0xF, true);  // quad xor1
    v += __builtin_bit_cast(float, x);
    x = __builtin_amdgcn_update_dpp(0, __builtin_bit_cast(int, v), 0x4E, 0xF, 0xF, true);  // quad xor2
    v += __builtin_bit_cast(float, x);
    x = __builtin_amdgcn_update_dpp(0, __builtin_bit_cast(int, v), 0x141, 0xF, 0xF, true); // row_half_mirror
    v += __builtin_bit_cast(float, x);
    x = __builtin_amdgcn_update_dpp(0, __builtin_bit_cast(int, v), 0x140, 0xF, 0xF, true); // row_mirror
    v += __builtin_bit_cast(float, x);
    return v;
}

// ---------------------------------------------------------------------------
// Kernel A: per-wave LIF recurrence, barrier-free. One wave per (b, 256-h
// slice): 512 blocks x 4 independent waves. Wout slice in registers. Writes
// 16 x 10 partial spike-sums per (t, b) to S for the LI kernel.
// ---------------------------------------------------------------------------
__global__ __launch_bounds__(256, 2)
void lif_scan(const float* __restrict__ Z, const float* __restrict__ Wout,
              float* __restrict__ S,
              float* __restrict__ st_v, float* __restrict__ st_i,
              int tn, int first, int last)
{
#pragma clang fp contract(off)   // mirror numpy's unfused mul/add rounding
    const int tid   = threadIdx.x;
    const int b     = blockIdx.x;
    const int lane  = tid & 63;
    const int w     = tid >> 6;
    const int hglob = w * 256 + lane * 4;

    float wreg[NOUT][4];
    #pragma unroll
    for (int o = 0; o < NOUT; ++o) {
        float4 t4 = *(const float4*)&Wout[o * HID + hglob];
        wreg[o][0] = t4.x; wreg[o][1] = t4.y; wreg[o][2] = t4.z; wreg[o][3] = t4.w;
    }

    float v[4], cu[4];
    if (first) {
        #pragma unroll
        for (int jj = 0; jj < 4; ++jj) { v[jj] = 0.f; cu[jj] = 0.f; }
    } else {
        float4 tv = *(const float4*)&st_v[(size_t)b * HID + hglob];
        float4 ti = *(const float4*)&st_i[(size_t)b * HID + hglob];
        v[0]=tv.x; v[1]=tv.y; v[2]=tv.z; v[3]=tv.w;
        cu[0]=ti.x; cu[1]=ti.y; cu[2]=ti.z; cu[3]=ti.w;
    }

    const float* Zb = Z + (size_t)b * HID + hglob;
    float4 z0 = *(const float4*)Zb;
    float4 z1 = (tn > 1) ? *(const float4*)(Zb + (size_t)BATCH * HID)     : z0;
    float4 z2 = (tn > 2) ? *(const float4*)(Zb + (size_t)2 * BATCH * HID) : z1;

    const int g = w * 4 + (lane >> 4);          // group 0..15

    for (int t = 0; t < tn; ++t) {
        float4 zc = z0; z0 = z1; z1 = z2;
        if (t + 3 < tn) z2 = *(const float4*)(Zb + (size_t)(t + 3) * BATCH * HID);

        const float za[4] = {zc.x, zc.y, zc.z, zc.w};
        float zf[4];
        bool anyz = false;
        #pragma unroll
        for (int jj = 0; jj < 4; ++jj) {
            float tmp  = (0.0f - v[jj]) + cu[jj];
            float vdec = v[jj] + 0.1f * tmp;
            bool  z    = vdec > 1.0f;
            zf[jj] = z ? 1.0f : 0.0f;
            anyz   = anyz || z;
            v[jj]  = z ? 0.0f : vdec;
            cu[jj] = cu[jj] * 0.8f + za[jj];
        }

        float p[NOUT];
        #pragma unroll
        for (int o = 0; o < NOUT; ++o) p[o] = 0.f;

        if (__any(anyz)) {
            if (anyz) {
                #pragma unroll
                for (int o = 0; o < NOUT; ++o)
                    p[o] = zf[0]*wreg[o][0] + zf[1]*wreg[o][1]
                         + zf[2]*wreg[o][2] + zf[3]*wreg[o][3];
            }
            #pragma unroll
            for (int o = 0; o < NOUT; ++o) p[o] = dpp_sum16(p[o]);
        }

        if ((lane & 15) == 0) {
            float* sp = S + ((size_t)t * BATCH + b) * (NGRP * NOUT) + g * NOUT;
            #pragma unroll
            for (int o = 0; o < NOUT; ++o) sp[o] = p[o];
        }
    }

    if (!last) {
        *(float4*)&st_v[(size_t)b * HID + hglob] = make_float4(v[0], v[1], v[2], v[3]);
        *(float4*)&st_i[(size_t)b * HID + hglob] = make_float4(cu[0], cu[1], cu[2], cu[3]);
    }
}

// ---------------------------------------------------------------------------
// Kernel B: LI output scan. One thread per (b, o): reduce 16 partials per
// step, run the 100-step leaky-integrator, write voltages.
// ---------------------------------------------------------------------------
__global__ __launch_bounds__(256)
void li_scan(const float* __restrict__ S, float* __restrict__ out,
             float* __restrict__ st_vli, float* __restrict__ st_ili,
             int t0, int tn, int first, int last)
{
#pragma clang fp contract(off)
    const int id = blockIdx.x * 256 + threadIdx.x;
    if (id >= BATCH * NOUT) return;
    const int b = id / NOUT;
    const int o = id - b * NOUT;

    float vli = 0.f, ili = 0.f;
    if (!first) { vli = st_vli[id]; ili = st_ili[id]; }

    const float* Sp = S + (size_t)b * (NGRP * NOUT) + o;
    for (int t = 0; t < tn; ++t) {
        const float* p = Sp + (size_t)t * BATCH * (NGRP * NOUT);
        float s = 0.f;
        #pragma unroll
        for (int gg = 0; gg < NGRP; ++gg) s += p[gg * NOUT];
        float tmp  = (0.0f - vli) + ili;
        float vnew = vli + 0.1f * tmp;
        ili = ili * 0.8f + s;
        vli = vnew;
        out[((size_t)(t0 + t) * BATCH + b) * NOUT + o] = vnew;
    }
    if (!last) { st_vli[id] = vli; st_ili[id] = ili; }
}

// ---------------------------------------------------------------------------
extern "C" void kernel_launch(void* const* d_in, const int* in_sizes, int n_in,
                              void* d_out, int out_size, void* d_ws, size_t ws_size,
                              hipStream_t stream)
{
    const float* x    = (const float*)d_in[0];   // [100, 512, 784]
    const float* W0   = (const float*)d_in[1];   // [1024, 784]
    const float* b0   = (const float*)d_in[2];   // [1024]
    const float* Wout = (const float*)d_in[3];   // [10, 1024]
    float* out = (float*)d_out;                  // [100, 512, 10]

    char* ws = (char*)d_ws;
    float* st_v   = (float*)ws;                          // 512*1024
    float* st_i   = st_v   + (size_t)BATCH * HID;        // 512*1024
    float* st_vli = st_i   + (size_t)BATCH * HID;        // 512*10
    float* st_ili = st_vli + BATCH * NOUT;               // 512*10
    _Float16* Whi = (_Float16*)(st_ili + BATCH * NOUT);  // 1024*800
    _Float16* Wlo = Whi + (size_t)HID * KP;              // 1024*800
    char* dyn = (char*)(Wlo + (size_t)HID * KP);

    const size_t fixed = (size_t)(dyn - ws);
    const size_t per_t = (size_t)BATCH * HID * 4          // Zbuf
                       + (size_t)BATCH * KP * 2 * 2       // Xhi + Xlo
                       + (size_t)BATCH * NGRP * NOUT * 4; // S partials
    size_t avail = (ws_size > fixed) ? ws_size - fixed : 0;
    int tch = (int)(avail / per_t);
    if (tch > T_TOT) tch = T_TOT;
    if (tch >= 2) tch &= ~1;          // keep mb % 8 == 0 for the XCD swizzle
    if (tch < 1) tch = 1;

    float*    Zbuf = (float*)dyn;
    _Float16* Xhi  = (_Float16*)(dyn + (size_t)tch * BATCH * HID * 4);
    _Float16* Xlo  = Xhi + (size_t)tch * BATCH * KP;
    float*    Sbuf = (float*)(Xlo + (size_t)tch * BATCH * KP);

    // W conversion once
    hipLaunchKernelGGL(cvt_split, dim3((HID * 100 + 255) / 256), dim3(256), 0, stream,
                       W0, Whi, Wlo, HID);

    for (int t0 = 0; t0 < T_TOT; t0 += tch) {
        const int tn    = (T_TOT - t0 < tch) ? (T_TOT - t0) : tch;
        const int nrows = tn * BATCH;
        const int mb    = nrows / 128;

        hipLaunchKernelGGL(cvt_split, dim3((nrows * 100 + 255) / 256), dim3(256), 0, stream,
                           x + (size_t)t0 * BATCH * FIN, Xhi, Xlo, nrows);
        hipLaunchKernelGGL(gemm_mfma, dim3(mb * 8), dim3(256), 0, stream,
                           Xhi, Xlo, Whi, Wlo, b0, Zbuf, mb);
        hipLaunchKernelGGL(lif_scan, dim3(BATCH), dim3(256), 0, stream,
                           Zbuf, Wout, Sbuf, st_v, st_i,
                           tn, (t0 == 0) ? 1 : 0, (t0 + tn >= T_TOT) ? 1 : 0);
        hipLaunchKernelGGL(li_scan, dim3((BATCH * NOUT + 255) / 256), dim3(256), 0, stream,
                           Sbuf, out, st_vli, st_ili,
                           t0, tn, (t0 == 0) ? 1 : 0, (t0 + tn >= T_TOT) ? 1 : 0);
    }
}

// Round 5
// 484.688 us; speedup vs baseline: 1.1133x; 1.0846x over previous
//
#include <hip/hip_runtime.h>

#define T_TOT 100
#define BATCH 512
#define FIN   784
#define HID   1024
#define NOUT  10
#define KP    800      // K padded to multiple of 32
#define BK    32
#define KSTEPS 25      // KP / BK
#define NGRP  16       // partial-sum groups per batch row (4 waves x 4)

typedef _Float16 f16x8 __attribute__((ext_vector_type(8)));
typedef float    f32x4 __attribute__((ext_vector_type(4)));

#define AS1C(p) ((const __attribute__((address_space(1))) void*)(p))
#define AS3(p)  ((__attribute__((address_space(3))) void*)(p))

// ---------------------------------------------------------------------------
// fp32 -> fp16 hi/lo split, row length 784 padded to 800.
//   hi = fp16(x);  lo = fp16((x - hi) * 4096)
// ---------------------------------------------------------------------------
__global__ __launch_bounds__(256)
void cvt_split(const float* __restrict__ src, _Float16* __restrict__ hi,
               _Float16* __restrict__ lo, int nrows)
{
    int idx = blockIdx.x * 256 + threadIdx.x;
    if (idx >= nrows * 100) return;
    int row = idx / 100;
    int k0  = (idx - row * 100) * 8;
    f16x8 h, l;
    if (k0 < FIN) {
        float4 a = *(const float4*)(src + (size_t)row * FIN + k0);
        float4 b = *(const float4*)(src + (size_t)row * FIN + k0 + 4);
        float xs[8] = {a.x, a.y, a.z, a.w, b.x, b.y, b.z, b.w};
        #pragma unroll
        for (int j = 0; j < 8; ++j) {
            _Float16 hh = (_Float16)xs[j];
            h[j] = hh;
            l[j] = (_Float16)((xs[j] - (float)hh) * 4096.0f);
        }
    } else {
        #pragma unroll
        for (int j = 0; j < 8; ++j) { h[j] = (_Float16)0.f; l[j] = (_Float16)0.f; }
    }
    *(f16x8*)(hi + (size_t)row * KP + k0) = h;
    *(f16x8*)(lo + (size_t)row * KP + k0) = l;
}

// ---------------------------------------------------------------------------
// Z = Xsplit · Wsplit^T + bias, fp16 MFMA 3-term split.
// Round-2 tile/fragment structure (verified bit-exact), new schedule:
// per K-step two phases (hi | lo), counted vmcnt(4) + raw s_barrier,
// stage of tile k+1 split across the two phases -> loads never drain mid-loop.
// ---------------------------------------------------------------------------
__global__ __launch_bounds__(256, 2)
void gemm_mfma(const _Float16* __restrict__ Xhi, const _Float16* __restrict__ Xlo,
               const _Float16* __restrict__ Whi, const _Float16* __restrict__ Wlo,
               const float* __restrict__ bias, float* __restrict__ Z, int mb)
{
    __shared__ char smem[65536];
    const int tid  = threadIdx.x;
    const int lane = tid & 63;
    const int wid  = tid >> 6;
    const int wm   = wid >> 1;
    const int wn   = wid & 1;
    const int fr   = lane & 15;
    const int fg   = lane >> 4;

    const int j = blockIdx.x;
    int bm, bn;
    if ((mb & 7) == 0) {          // XCD-friendly: all 8 bn of a bm share blockIdx%8
        bm = (j & 7) | ((j >> 6) << 3);
        bn = (j >> 3) & 7;
    } else {
        bm = j >> 3;
        bn = j & 7;
    }
    const size_t row0 = (size_t)bm * 128;
    const int    col0 = bn * 128;

    f32x4 accm[4][4], accc[4][4];
    #pragma unroll
    for (int a = 0; a < 4; ++a)
        #pragma unroll
        for (int b = 0; b < 4; ++b) {
            accm[a][b] = (f32x4){0.f, 0.f, 0.f, 0.f};
            accc[a][b] = (f32x4){0.f, 0.f, 0.f, 0.f};
        }

    // hi-half stage: Ahi + Bhi of tile kt -> buffer buf (4 loads/thread)
    auto stage_hi = [&](int buf, int kt) {
        const int kof = kt * BK;
        #pragma unroll
        for (int q = 0; q < 2; ++q) {
            const int lin = q * 256 + tid;
            const int row = lin >> 2;
            const int pos = lin & 3;
            const int gg  = pos ^ ((row >> 1) & 3);  // inverse chunk swizzle
            const int ldsw = buf * 32768 + q * 4096 + wid * 1024;
            const size_t ga = (row0 + row) * (size_t)KP + kof + gg * 8;
            const size_t gb = (size_t)(col0 + row) * KP + kof + gg * 8;
            __builtin_amdgcn_global_load_lds(AS1C(Xhi + ga), AS3(smem + ldsw),         16, 0, 0);
            __builtin_amdgcn_global_load_lds(AS1C(Whi + gb), AS3(smem + ldsw + 16384), 16, 0, 0);
        }
    };
    // lo-half stage: Alo + Blo of tile kt -> buffer buf (4 loads/thread)
    auto stage_lo = [&](int buf, int kt) {
        const int kof = kt * BK;
        #pragma unroll
        for (int q = 0; q < 2; ++q) {
            const int lin = q * 256 + tid;
            const int row = lin >> 2;
            const int pos = lin & 3;
            const int gg  = pos ^ ((row >> 1) & 3);
            const int ldsw = buf * 32768 + q * 4096 + wid * 1024;
            const size_t ga = (row0 + row) * (size_t)KP + kof + gg * 8;
            const size_t gb = (size_t)(col0 + row) * KP + kof + gg * 8;
            __builtin_amdgcn_global_load_lds(AS1C(Xlo + ga), AS3(smem + ldsw +  8192), 16, 0, 0);
            __builtin_amdgcn_global_load_lds(AS1C(Wlo + gb), AS3(smem + ldsw + 24576), 16, 0, 0);
        }
    };

    stage_hi(0, 0);
    stage_lo(0, 0);

    for (int kt = 0; kt < KSTEPS; ++kt) {
        const int buf = kt & 1;
        const char* base = smem + buf * 32768;
        f16x8 ah[4], al[4], bh[4], bl[4];

        // ---- Phase A: hi MFMAs (accm) --------------------------------------
        asm volatile("s_waitcnt vmcnt(4)" ::: "memory");   // hi(kt) landed
        __builtin_amdgcn_s_barrier();
        asm volatile("" ::: "memory");
        if (kt + 1 < KSTEPS) stage_hi(buf ^ 1, kt + 1);

        #pragma unroll
        for (int mf = 0; mf < 4; ++mf) {
            const int row = wm * 64 + mf * 16 + fr;
            const int off = row * 64 + ((fg ^ ((row >> 1) & 3)) << 4);
            ah[mf] = *(const f16x8*)(base + off);
        }
        #pragma unroll
        for (int nf = 0; nf < 4; ++nf) {
            const int row = wn * 64 + nf * 16 + fr;
            const int off = row * 64 + ((fg ^ ((row >> 1) & 3)) << 4);
            bh[nf] = *(const f16x8*)(base + 16384 + off);
        }
        __builtin_amdgcn_s_setprio(1);
        #pragma unroll
        for (int mf = 0; mf < 4; ++mf)
            #pragma unroll
            for (int nf = 0; nf < 4; ++nf)
                accm[mf][nf] = __builtin_amdgcn_mfma_f32_16x16x32_f16(ah[mf], bh[nf], accm[mf][nf], 0, 0, 0);
        __builtin_amdgcn_s_setprio(0);

        // ---- Phase B: cross-term MFMAs (accc) ------------------------------
        if (kt + 1 < KSTEPS) asm volatile("s_waitcnt vmcnt(4)" ::: "memory");  // lo(kt) landed
        else                 asm volatile("s_waitcnt vmcnt(0)" ::: "memory");
        __builtin_amdgcn_s_barrier();
        asm volatile("" ::: "memory");
        if (kt + 1 < KSTEPS) stage_lo(buf ^ 1, kt + 1);

        #pragma unroll
        for (int mf = 0; mf < 4; ++mf) {
            const int row = wm * 64 + mf * 16 + fr;
            const int off = row * 64 + ((fg ^ ((row >> 1) & 3)) << 4);
            al[mf] = *(const f16x8*)(base + 8192 + off);
        }
        #pragma unroll
        for (int nf = 0; nf < 4; ++nf) {
            const int row = wn * 64 + nf * 16 + fr;
            const int off = row * 64 + ((fg ^ ((row >> 1) & 3)) << 4);
            bl[nf] = *(const f16x8*)(base + 24576 + off);
        }
        __builtin_amdgcn_s_setprio(1);
        #pragma unroll
        for (int mf = 0; mf < 4; ++mf)
            #pragma unroll
            for (int nf = 0; nf < 4; ++nf) {
                accc[mf][nf] = __builtin_amdgcn_mfma_f32_16x16x32_f16(ah[mf], bl[nf], accc[mf][nf], 0, 0, 0);
                accc[mf][nf] = __builtin_amdgcn_mfma_f32_16x16x32_f16(al[mf], bh[nf], accc[mf][nf], 0, 0, 0);
            }
        __builtin_amdgcn_s_setprio(0);
    }

    #pragma unroll
    for (int nf = 0; nf < 4; ++nf) {
        const int colg = col0 + wn * 64 + nf * 16 + fr;
        const float bv = bias[colg];
        #pragma unroll
        for (int mf = 0; mf < 4; ++mf) {
            const size_t rowg = row0 + wm * 64 + mf * 16 + fg * 4;
            #pragma unroll
            for (int i = 0; i < 4; ++i)
                Z[(rowg + i) * HID + colg] =
                    accm[mf][nf][i] + accc[mf][nf][i] * 2.44140625e-4f + bv;
        }
    }
}

// ---------------------------------------------------------------------------
// DPP 4-level add-reduce: per-16-lane-group sum, result in ALL lanes (VALU)
// ---------------------------------------------------------------------------
__device__ __forceinline__ float dpp_sum16(float v)
{
    int x;
    x = __builtin_amdgcn_update_dpp(0, __builtin_bit_cast(int, v), 0xB1, 0xF, 0xF, true);  // quad xor1
    v += __builtin_bit_cast(float, x);
    x = __builtin_amdgcn_update_dpp(0, __builtin_bit_cast(int, v), 0x4E, 0xF, 0xF, true);  // quad xor2
    v += __builtin_bit_cast(float, x);
    x = __builtin_amdgcn_update_dpp(0, __builtin_bit_cast(int, v), 0x141, 0xF, 0xF, true); // row_half_mirror
    v += __builtin_bit_cast(float, x);
    x = __builtin_amdgcn_update_dpp(0, __builtin_bit_cast(int, v), 0x140, 0xF, 0xF, true); // row_mirror
    v += __builtin_bit_cast(float, x);
    return v;
}

// ---------------------------------------------------------------------------
// Kernel A: per-wave LIF recurrence, barrier-free, 8-deep register-ring
// Z prefetch (static ring indices via unroll-by-8 nest).
// ---------------------------------------------------------------------------
__global__ __launch_bounds__(256, 2)
void lif_scan(const float* __restrict__ Z, const float* __restrict__ Wout,
              float* __restrict__ S,
              float* __restrict__ st_v, float* __restrict__ st_i,
              int tn, int first, int last)
{
#pragma clang fp contract(off)   // mirror numpy's unfused mul/add rounding
    const int tid   = threadIdx.x;
    const int b     = blockIdx.x;
    const int lane  = tid & 63;
    const int w     = tid >> 6;
    const int hglob = w * 256 + lane * 4;

    float wreg[NOUT][4];
    #pragma unroll
    for (int o = 0; o < NOUT; ++o) {
        float4 t4 = *(const float4*)&Wout[o * HID + hglob];
        wreg[o][0] = t4.x; wreg[o][1] = t4.y; wreg[o][2] = t4.z; wreg[o][3] = t4.w;
    }

    float v[4], cu[4];
    if (first) {
        #pragma unroll
        for (int jj = 0; jj < 4; ++jj) { v[jj] = 0.f; cu[jj] = 0.f; }
    } else {
        float4 tv = *(const float4*)&st_v[(size_t)b * HID + hglob];
        float4 ti = *(const float4*)&st_i[(size_t)b * HID + hglob];
        v[0]=tv.x; v[1]=tv.y; v[2]=tv.z; v[3]=tv.w;
        cu[0]=ti.x; cu[1]=ti.y; cu[2]=ti.z; cu[3]=ti.w;
    }

    const float*  Zb    = Z + (size_t)b * HID + hglob;
    const size_t  ZSTEP = (size_t)BATCH * HID;
    const int     g     = w * 4 + (lane >> 4);   // group 0..15

    float4 ring[8];
    #pragma unroll
    for (int u = 0; u < 8; ++u)
        ring[u] = (u < tn) ? *(const float4*)(Zb + (size_t)u * ZSTEP)
                           : make_float4(0.f, 0.f, 0.f, 0.f);

    for (int tb = 0; tb < tn; tb += 8) {
        #pragma unroll
        for (int u = 0; u < 8; ++u) {
            const int t = tb + u;
            if (t >= tn) break;
            float4 zc = ring[u];
            if (t + 8 < tn)
                ring[u] = *(const float4*)(Zb + (size_t)(t + 8) * ZSTEP);

            const float za[4] = {zc.x, zc.y, zc.z, zc.w};
            float zf[4];
            bool anyz = false;
            #pragma unroll
            for (int jj = 0; jj < 4; ++jj) {
                float tmp  = (0.0f - v[jj]) + cu[jj];
                float vdec = v[jj] + 0.1f * tmp;
                bool  z    = vdec > 1.0f;
                zf[jj] = z ? 1.0f : 0.0f;
                anyz   = anyz || z;
                v[jj]  = z ? 0.0f : vdec;
                cu[jj] = cu[jj] * 0.8f + za[jj];
            }

            float p[NOUT];
            #pragma unroll
            for (int o = 0; o < NOUT; ++o) p[o] = 0.f;

            if (__any(anyz)) {
                if (anyz) {
                    #pragma unroll
                    for (int o = 0; o < NOUT; ++o)
                        p[o] = zf[0]*wreg[o][0] + zf[1]*wreg[o][1]
                             + zf[2]*wreg[o][2] + zf[3]*wreg[o][3];
                }
                #pragma unroll
                for (int o = 0; o < NOUT; ++o) p[o] = dpp_sum16(p[o]);
            }

            if ((lane & 15) == 0) {
                float* sp = S + ((size_t)t * BATCH + b) * (NGRP * NOUT) + g * NOUT;
                #pragma unroll
                for (int o = 0; o < NOUT; ++o) sp[o] = p[o];
            }
        }
    }

    if (!last) {
        *(float4*)&st_v[(size_t)b * HID + hglob] = make_float4(v[0], v[1], v[2], v[3]);
        *(float4*)&st_i[(size_t)b * HID + hglob] = make_float4(cu[0], cu[1], cu[2], cu[3]);
    }
}

// ---------------------------------------------------------------------------
// Kernel B: LI output scan. One thread per (b, o).
// ---------------------------------------------------------------------------
__global__ __launch_bounds__(256)
void li_scan(const float* __restrict__ S, float* __restrict__ out,
             float* __restrict__ st_vli, float* __restrict__ st_ili,
             int t0, int tn, int first, int last)
{
#pragma clang fp contract(off)
    const int id = blockIdx.x * 256 + threadIdx.x;
    if (id >= BATCH * NOUT) return;
    const int b = id / NOUT;
    const int o = id - b * NOUT;

    float vli = 0.f, ili = 0.f;
    if (!first) { vli = st_vli[id]; ili = st_ili[id]; }

    const float* Sp = S + (size_t)b * (NGRP * NOUT) + o;
    for (int t = 0; t < tn; ++t) {
        const float* p = Sp + (size_t)t * BATCH * (NGRP * NOUT);
        float s = 0.f;
        #pragma unroll
        for (int gg = 0; gg < NGRP; ++gg) s += p[gg * NOUT];
        float tmp  = (0.0f - vli) + ili;
        float vnew = vli + 0.1f * tmp;
        ili = ili * 0.8f + s;
        vli = vnew;
        out[((size_t)(t0 + t) * BATCH + b) * NOUT + o] = vnew;
    }
    if (!last) { st_vli[id] = vli; st_ili[id] = ili; }
}

// ---------------------------------------------------------------------------
extern "C" void kernel_launch(void* const* d_in, const int* in_sizes, int n_in,
                              void* d_out, int out_size, void* d_ws, size_t ws_size,
                              hipStream_t stream)
{
    const float* x    = (const float*)d_in[0];   // [100, 512, 784]
    const float* W0   = (const float*)d_in[1];   // [1024, 784]
    const float* b0   = (const float*)d_in[2];   // [1024]
    const float* Wout = (const float*)d_in[3];   // [10, 1024]
    float* out = (float*)d_out;                  // [100, 512, 10]

    char* ws = (char*)d_ws;
    float* st_v   = (float*)ws;                          // 512*1024
    float* st_i   = st_v   + (size_t)BATCH * HID;        // 512*1024
    float* st_vli = st_i   + (size_t)BATCH * HID;        // 512*10
    float* st_ili = st_vli + BATCH * NOUT;               // 512*10
    _Float16* Whi = (_Float16*)(st_ili + BATCH * NOUT);  // 1024*800
    _Float16* Wlo = Whi + (size_t)HID * KP;              // 1024*800
    char* dyn = (char*)(Wlo + (size_t)HID * KP);

    const size_t fixed = (size_t)(dyn - ws);
    const size_t per_t = (size_t)BATCH * HID * 4          // Zbuf
                       + (size_t)BATCH * KP * 2 * 2       // Xhi + Xlo
                       + (size_t)BATCH * NGRP * NOUT * 4; // S partials
    size_t avail = (ws_size > fixed) ? ws_size - fixed : 0;
    int tch = (int)(avail / per_t);
    if (tch > T_TOT) tch = T_TOT;
    if (tch >= 2) tch &= ~1;          // keep mb % 8 == 0 for the XCD swizzle
    if (tch < 1) tch = 1;

    float*    Zbuf = (float*)dyn;
    _Float16* Xhi  = (_Float16*)(dyn + (size_t)tch * BATCH * HID * 4);
    _Float16* Xlo  = Xhi + (size_t)tch * BATCH * KP;
    float*    Sbuf = (float*)(Xlo + (size_t)tch * BATCH * KP);

    // W conversion once
    hipLaunchKernelGGL(cvt_split, dim3((HID * 100 + 255) / 256), dim3(256), 0, stream,
                       W0, Whi, Wlo, HID);

    for (int t0 = 0; t0 < T_TOT; t0 += tch) {
        const int tn    = (T_TOT - t0 < tch) ? (T_TOT - t0) : tch;
        const int nrows = tn * BATCH;
        const int mb    = nrows / 128;

        hipLaunchKernelGGL(cvt_split, dim3((nrows * 100 + 255) / 256), dim3(256), 0, stream,
                           x + (size_t)t0 * BATCH * FIN, Xhi, Xlo, nrows);
        hipLaunchKernelGGL(gemm_mfma, dim3(mb * 8), dim3(256), 0, stream,
                           Xhi, Xlo, Whi, Wlo, b0, Zbuf, mb);
        hipLaunchKernelGGL(lif_scan, dim3(BATCH), dim3(256), 0, stream,
                           Zbuf, Wout, Sbuf, st_v, st_i,
                           tn, (t0 == 0) ? 1 : 0, (t0 + tn >= T_TOT) ? 1 : 0);
        hipLaunchKernelGGL(li_scan, dim3((BATCH * NOUT + 255) / 256), dim3(256), 0, stream,
                           Sbuf, out, st_vli, st_ili,
                           t0, tn, (t0 == 0) ? 1 : 0, (t0 + tn >= T_TOT) ? 1 : 0);
    }
}

// Round 8
// 450.291 us; speedup vs baseline: 1.1983x; 1.0764x over previous
//
#include <hip/hip_runtime.h>

#define T_TOT 100
#define BATCH 512
#define FIN   784
#define HID   1024
#define NOUT  10
#define KP    800      // K padded to multiple of 32 (W only)
#define BK    32
#define KSTEPS 25      // ceil(784/32) = 25 (last tile k 768..799, zero-padded)
#define NGRP  16       // partial-sum groups per batch row (4 waves x 4)

#define A_HI 0
#define A_LO 8192
#define B_HI 16384
#define B_LO 24576

typedef _Float16 f16x8 __attribute__((ext_vector_type(8)));
typedef float    f32x4 __attribute__((ext_vector_type(4)));

#define AS1C(p) ((const __attribute__((address_space(1))) void*)(p))
#define AS3(p)  ((__attribute__((address_space(3))) void*)(p))

// ---------------------------------------------------------------------------
// fp32 -> fp16 hi/lo split (SCALED lo, the bit-proven scheme), used for W only.
//   hi = fp16(x);  lo = fp16((x - hi) * 4096)
// ---------------------------------------------------------------------------
__global__ __launch_bounds__(256)
void cvt_split(const float* __restrict__ src, _Float16* __restrict__ hi,
               _Float16* __restrict__ lo, int nrows)
{
    int idx = blockIdx.x * 256 + threadIdx.x;
    if (idx >= nrows * 100) return;
    int row = idx / 100;
    int k0  = (idx - row * 100) * 8;
    f16x8 h, l;
    if (k0 < FIN) {
        float4 a = *(const float4*)(src + (size_t)row * FIN + k0);
        float4 b = *(const float4*)(src + (size_t)row * FIN + k0 + 4);
        float xs[8] = {a.x, a.y, a.z, a.w, b.x, b.y, b.z, b.w};
        #pragma unroll
        for (int j = 0; j < 8; ++j) {
            _Float16 hh = (_Float16)xs[j];
            h[j] = hh;
            l[j] = (_Float16)((xs[j] - (float)hh) * 4096.0f);
        }
    } else {
        #pragma unroll
        for (int j = 0; j < 8; ++j) { h[j] = (_Float16)0.f; l[j] = (_Float16)0.f; }
    }
    *(f16x8*)(hi + (size_t)row * KP + k0) = h;
    *(f16x8*)(lo + (size_t)row * KP + k0) = l;
}

// ---------------------------------------------------------------------------
// Z = X · Wsplit^T + bias, fp16 MFMA 3-term split, dual accumulators.
// Round-2/5 geometry (128x128 tile, BK=32, 4 waves 2x2, wave tile 64x64,
// 64KB double-buffered LDS, chunk-XOR swizzle both sides).
// X read as raw fp32, hi/lo-split IN-KERNEL (reg-stage + swizzled ds_write);
// W (pre-split once) stages via global_load_lds w16.
// ---------------------------------------------------------------------------
__global__ __launch_bounds__(256, 2)
void gemm_fused(const float* __restrict__ X,
                const _Float16* __restrict__ Whi, const _Float16* __restrict__ Wlo,
                const float* __restrict__ bias, float* __restrict__ Z, int mb)
{
    __shared__ char smem[65536];
    const int tid  = threadIdx.x;
    const int lane = tid & 63;
    const int wid  = tid >> 6;
    const int wm   = wid >> 1;
    const int wn   = wid & 1;
    const int fr   = lane & 15;
    const int fg   = lane >> 4;

    const int j = blockIdx.x;
    int bm, bn;
    if ((mb & 7) == 0) {          // XCD-friendly: all 8 bn of a bm share blockIdx%8
        bm = (j & 7) | ((j >> 6) << 3);
        bn = (j >> 3) & 7;
    } else {
        bm = j >> 3;
        bn = j & 7;
    }
    const size_t row0 = (size_t)bm * 128;
    const int    col0 = bn * 128;

    f32x4 accm[4][4], accc[4][4];
    #pragma unroll
    for (int a = 0; a < 4; ++a)
        #pragma unroll
        for (int b = 0; b < 4; ++b) {
            accm[a][b] = (f32x4){0.f, 0.f, 0.f, 0.f};
            accc[a][b] = (f32x4){0.f, 0.f, 0.f, 0.f};
        }

    // ---- A-side: fp32 loads to regs (fused conversion) ---------------------
    const int arow  = tid >> 1;          // 0..127
    const int ahalf = tid & 1;           // which 16-k half of the 32-k tile
    float4 ar[4];
    auto aload = [&](int kt) {
        const int kof = kt * BK + ahalf * 16;
        const float* src = X + (row0 + arow) * (size_t)FIN + kof;
        #pragma unroll
        for (int c = 0; c < 4; ++c)
            ar[c] = (kof + c * 4 < FIN) ? *(const float4*)(src + c * 4)
                                        : make_float4(0.f, 0.f, 0.f, 0.f);
    };
    auto cvtwrite = [&](int buf) {       // split ar -> swizzled LDS hi/lo
        char* base = smem + buf * 32768;
        #pragma unroll
        for (int cc = 0; cc < 2; ++cc) {
            float xs[8];
            *(float4*)&xs[0] = ar[cc * 2];
            *(float4*)&xs[4] = ar[cc * 2 + 1];
            f16x8 h, l;
            #pragma unroll
            for (int e = 0; e < 8; ++e) {
                _Float16 hh = (_Float16)xs[e];
                h[e] = hh;
                l[e] = (_Float16)((xs[e] - (float)hh) * 4096.0f);
            }
            const int ch  = ahalf * 2 + cc;           // logical k-chunk 0..3
            const int chs = ch ^ ((arow >> 1) & 3);   // chunk XOR swizzle
            const int off = arow * 64 + chs * 16;
            *(f16x8*)(base + A_HI + off) = h;
            *(f16x8*)(base + A_LO + off) = l;
        }
    };
    // ---- B-side: global_load_lds from pre-split W --------------------------
    auto stageB = [&](int buf, int kt) {
        const int kof = kt * BK;
        #pragma unroll
        for (int q = 0; q < 2; ++q) {
            const int lin = q * 256 + tid;
            const int row = lin >> 2;
            const int pos = lin & 3;
            const int gg  = pos ^ ((row >> 1) & 3);   // inverse chunk swizzle
            const int ldsw = buf * 32768 + q * 4096 + wid * 1024;
            const size_t gb = (size_t)(col0 + row) * KP + kof + gg * 8;
            __builtin_amdgcn_global_load_lds(AS1C(Whi + gb), AS3(smem + ldsw + B_HI), 16, 0, 0);
            __builtin_amdgcn_global_load_lds(AS1C(Wlo + gb), AS3(smem + ldsw + B_LO), 16, 0, 0);
        }
    };

    auto compute = [&](int buf) {
        const char* base = smem + buf * 32768;
        f16x8 ah[4], al[4], bh[4], bl[4];
        #pragma unroll
        for (int mf = 0; mf < 4; ++mf) {
            const int row = wm * 64 + mf * 16 + fr;
            const int off = row * 64 + ((fg ^ ((row >> 1) & 3)) << 4);
            ah[mf] = *(const f16x8*)(base + A_HI + off);
            al[mf] = *(const f16x8*)(base + A_LO + off);
        }
        #pragma unroll
        for (int nf = 0; nf < 4; ++nf) {
            const int row = wn * 64 + nf * 16 + fr;
            const int off = row * 64 + ((fg ^ ((row >> 1) & 3)) << 4);
            bh[nf] = *(const f16x8*)(base + B_HI + off);
            bl[nf] = *(const f16x8*)(base + B_LO + off);
        }
        #pragma unroll
        for (int mf = 0; mf < 4; ++mf)
            #pragma unroll
            for (int nf = 0; nf < 4; ++nf) {
                accm[mf][nf] = __builtin_amdgcn_mfma_f32_16x16x32_f16(ah[mf], bh[nf], accm[mf][nf], 0, 0, 0);
                accc[mf][nf] = __builtin_amdgcn_mfma_f32_16x16x32_f16(ah[mf], bl[nf], accc[mf][nf], 0, 0, 0);
                accc[mf][nf] = __builtin_amdgcn_mfma_f32_16x16x32_f16(al[mf], bh[nf], accc[mf][nf], 0, 0, 0);
            }
    };

    // prologue: fill buffer 0
    aload(0);
    stageB(0, 0);
    cvtwrite(0);

    int buf = 0;
    for (int kt = 0; kt < KSTEPS; ++kt) {
        __syncthreads();                  // drains vmcnt (B DMA) + lgkm (A writes)
        if (kt + 1 < KSTEPS) {            // buf^1 readers retired at this barrier
            aload(kt + 1);                //   issue A fp32 loads (regs)
            stageB(buf ^ 1, kt + 1);      //   issue B DMA
        }
        compute(buf);                     // MFMA on current buffer
        if (kt + 1 < KSTEPS) cvtwrite(buf ^ 1);   // convert+write after compute
        buf ^= 1;
    }

    #pragma unroll
    for (int nf = 0; nf < 4; ++nf) {
        const int colg = col0 + wn * 64 + nf * 16 + fr;
        const float bv = bias[colg];
        #pragma unroll
        for (int mf = 0; mf < 4; ++mf) {
            const size_t rowg = row0 + wm * 64 + mf * 16 + fg * 4;
            #pragma unroll
            for (int i = 0; i < 4; ++i)
                Z[(rowg + i) * HID + colg] =
                    accm[mf][nf][i] + accc[mf][nf][i] * 2.44140625e-4f + bv;
        }
    }
}

// ---------------------------------------------------------------------------
// DPP 4-level add-reduce: per-16-lane-group sum, result in ALL lanes (VALU)
// ---------------------------------------------------------------------------
__device__ __forceinline__ float dpp_sum16(float v)
{
    int x;
    x = __builtin_amdgcn_update_dpp(0, __builtin_bit_cast(int, v), 0xB1, 0xF, 0xF, true);  // quad xor1
    v += __builtin_bit_cast(float, x);
    x = __builtin_amdgcn_update_dpp(0, __builtin_bit_cast(int, v), 0x4E, 0xF, 0xF, true);  // quad xor2
    v += __builtin_bit_cast(float, x);
    x = __builtin_amdgcn_update_dpp(0, __builtin_bit_cast(int, v), 0x141, 0xF, 0xF, true); // row_half_mirror
    v += __builtin_bit_cast(float, x);
    x = __builtin_amdgcn_update_dpp(0, __builtin_bit_cast(int, v), 0x140, 0xF, 0xF, true); // row_mirror
    v += __builtin_bit_cast(float, x);
    return v;
}

// ---------------------------------------------------------------------------
// Kernel A: per-wave LIF recurrence, barrier-free, 8-deep register-ring
// Z prefetch (static ring indices via unroll-by-8 nest). Scalar S stores.
// ---------------------------------------------------------------------------
__global__ __launch_bounds__(256, 2)
void lif_scan(const float* __restrict__ Z, const float* __restrict__ Wout,
              float* __restrict__ S,
              float* __restrict__ st_v, float* __restrict__ st_i,
              int tn, int first, int last)
{
#pragma clang fp contract(off)   // mirror numpy's unfused mul/add rounding
    const int tid   = threadIdx.x;
    const int b     = blockIdx.x;
    const int lane  = tid & 63;
    const int w     = tid >> 6;
    const int hglob = w * 256 + lane * 4;

    float wreg[NOUT][4];
    #pragma unroll
    for (int o = 0; o < NOUT; ++o) {
        float4 t4 = *(const float4*)&Wout[o * HID + hglob];
        wreg[o][0] = t4.x; wreg[o][1] = t4.y; wreg[o][2] = t4.z; wreg[o][3] = t4.w;
    }

    float v[4], cu[4];
    if (first) {
        #pragma unroll
        for (int jj = 0; jj < 4; ++jj) { v[jj] = 0.f; cu[jj] = 0.f; }
    } else {
        float4 tv = *(const float4*)&st_v[(size_t)b * HID + hglob];
        float4 ti = *(const float4*)&st_i[(size_t)b * HID + hglob];
        v[0]=tv.x; v[1]=tv.y; v[2]=tv.z; v[3]=tv.w;
        cu[0]=ti.x; cu[1]=ti.y; cu[2]=ti.z; cu[3]=ti.w;
    }

    const float*  Zb    = Z + (size_t)b * HID + hglob;
    const size_t  ZSTEP = (size_t)BATCH * HID;
    const int     g     = w * 4 + (lane >> 4);   // group 0..15

    float4 ring[8];
    #pragma unroll
    for (int u = 0; u < 8; ++u)
        ring[u] = (u < tn) ? *(const float4*)(Zb + (size_t)u * ZSTEP)
                           : make_float4(0.f, 0.f, 0.f, 0.f);

    for (int tb = 0; tb < tn; tb += 8) {
        #pragma unroll
        for (int u = 0; u < 8; ++u) {
            const int t = tb + u;
            if (t >= tn) break;
            float4 zc = ring[u];
            if (t + 8 < tn)
                ring[u] = *(const float4*)(Zb + (size_t)(t + 8) * ZSTEP);

            const float za[4] = {zc.x, zc.y, zc.z, zc.w};
            float zf[4];
            bool anyz = false;
            #pragma unroll
            for (int jj = 0; jj < 4; ++jj) {
                float tmp  = (0.0f - v[jj]) + cu[jj];
                float vdec = v[jj] + 0.1f * tmp;
                bool  z    = vdec > 1.0f;
                zf[jj] = z ? 1.0f : 0.0f;
                anyz   = anyz || z;
                v[jj]  = z ? 0.0f : vdec;
                cu[jj] = cu[jj] * 0.8f + za[jj];
            }

            float p[NOUT];
            #pragma unroll
            for (int o = 0; o < NOUT; ++o) p[o] = 0.f;

            if (__any(anyz)) {
                if (anyz) {
                    #pragma unroll
                    for (int o = 0; o < NOUT; ++o)
                        p[o] = zf[0]*wreg[o][0] + zf[1]*wreg[o][1]
                             + zf[2]*wreg[o][2] + zf[3]*wreg[o][3];
                }
                #pragma unroll
                for (int o = 0; o < NOUT; ++o) p[o] = dpp_sum16(p[o]);
            }

            if ((lane & 15) == 0) {
                float* sp = S + ((size_t)t * BATCH + b) * (NGRP * NOUT) + g * NOUT;
                #pragma unroll
                for (int o = 0; o < NOUT; ++o) sp[o] = p[o];
            }
        }
    }

    if (!last) {
        *(float4*)&st_v[(size_t)b * HID + hglob] = make_float4(v[0], v[1], v[2], v[3]);
        *(float4*)&st_i[(size_t)b * HID + hglob] = make_float4(cu[0], cu[1], cu[2], cu[3]);
    }
}

// ---------------------------------------------------------------------------
// Kernel B: LI output scan, PARALLEL: 16 lanes per (b,o) team, DPP-16 reduce,
// redundant per-lane recurrence, 4-deep t-prefetch. 320 blocks x 256 thr.
// ---------------------------------------------------------------------------
__global__ __launch_bounds__(256)
void li_scan(const float* __restrict__ S, float* __restrict__ out,
             float* __restrict__ st_vli, float* __restrict__ st_ili,
             int t0, int tn, int first, int last)
{
#pragma clang fp contract(off)
    const int team = blockIdx.x * 16 + (threadIdx.x >> 4);   // 0..5119
    const int g    = threadIdx.x & 15;
    const int b    = team / NOUT;
    const int o    = team - b * NOUT;

    float vli = 0.f, ili = 0.f;
    if (!first) { vli = st_vli[team]; ili = st_ili[team]; }

    const float* Sp   = S + ((size_t)b * NGRP + g) * NOUT + o;
    const size_t STEP = (size_t)BATCH * NGRP * NOUT;

    float rg[4];
    #pragma unroll
    for (int u = 0; u < 4; ++u)
        rg[u] = (u < tn) ? Sp[(size_t)u * STEP] : 0.f;

    for (int tb = 0; tb < tn; tb += 4) {
        #pragma unroll
        for (int u = 0; u < 4; ++u) {
            const int t = tb + u;
            if (t >= tn) break;
            float val = rg[u];
            if (t + 4 < tn) rg[u] = Sp[(size_t)(t + 4) * STEP];
            float s = dpp_sum16(val);
            float tmp  = (0.0f - vli) + ili;
            float vnew = vli + 0.1f * tmp;
            ili = ili * 0.8f + s;
            vli = vnew;
            if (g == 0)
                out[((size_t)(t0 + t) * BATCH + b) * NOUT + o] = vnew;
        }
    }
    if (!last && g == 0) { st_vli[team] = vli; st_ili[team] = ili; }
}

// ---------------------------------------------------------------------------
extern "C" void kernel_launch(void* const* d_in, const int* in_sizes, int n_in,
                              void* d_out, int out_size, void* d_ws, size_t ws_size,
                              hipStream_t stream)
{
    const float* x    = (const float*)d_in[0];   // [100, 512, 784]
    const float* W0   = (const float*)d_in[1];   // [1024, 784]
    const float* b0   = (const float*)d_in[2];   // [1024]
    const float* Wout = (const float*)d_in[3];   // [10, 1024]
    float* out = (float*)d_out;                  // [100, 512, 10]

    char* ws = (char*)d_ws;
    float* st_v   = (float*)ws;                          // 512*1024
    float* st_i   = st_v   + (size_t)BATCH * HID;        // 512*1024
    float* st_vli = st_i   + (size_t)BATCH * HID;        // 512*10
    float* st_ili = st_vli + BATCH * NOUT;               // 512*10
    _Float16* Whi = (_Float16*)(st_ili + BATCH * NOUT);  // 1024*800
    _Float16* Wlo = Whi + (size_t)HID * KP;              // 1024*800
    char* dyn = (char*)(Wlo + (size_t)HID * KP);

    const size_t fixed = (size_t)(dyn - ws);
    const size_t per_t = (size_t)BATCH * HID * 4          // Zbuf
                       + (size_t)BATCH * NGRP * NOUT * 4; // S partials
    size_t avail = (ws_size > fixed) ? ws_size - fixed : 0;
    int tch = (int)(avail / per_t);
    if (tch > T_TOT) tch = T_TOT;
    if (tch >= 2) tch &= ~1;          // keep mb % 8 == 0 for the XCD swizzle
    if (tch < 1) tch = 1;

    float* Zbuf = (float*)dyn;
    float* Sbuf = (float*)(dyn + (size_t)tch * BATCH * HID * 4);

    // W conversion once (tiny)
    hipLaunchKernelGGL(cvt_split, dim3((HID * 100 + 255) / 256), dim3(256), 0, stream,
                       W0, Whi, Wlo, HID);

    for (int t0 = 0; t0 < T_TOT; t0 += tch) {
        const int tn    = (T_TOT - t0 < tch) ? (T_TOT - t0) : tch;
        const int nrows = tn * BATCH;
        const int mb    = nrows / 128;

        hipLaunchKernelGGL(gemm_fused, dim3(mb * 8), dim3(256), 0, stream,
                           x + (size_t)t0 * BATCH * FIN, Whi, Wlo, b0, Zbuf, mb);
        hipLaunchKernelGGL(lif_scan, dim3(BATCH), dim3(256), 0, stream,
                           Zbuf, Wout, Sbuf, st_v, st_i,
                           tn, (t0 == 0) ? 1 : 0, (t0 + tn >= T_TOT) ? 1 : 0);
        hipLaunchKernelGGL(li_scan, dim3((BATCH * NOUT) / 16), dim3(256), 0, stream,
                           Sbuf, out, st_vli, st_ili,
                           t0, tn, (t0 == 0) ? 1 : 0, (t0 + tn >= T_TOT) ? 1 : 0);
    }
}